// Round 1
// baseline (13237.439 us; speedup 1.0000x reference)
//
#include <hip/hip_runtime.h>

// LightGCN 3-layer propagation for NCLModel_91070486544456.
//
// Sizes (fixed by the reference):
//   user_emb [500000][64] f32, item_emb [200000][64] f32, edge_index [2][5000000] i32
// Output (concatenated flat, f32):
//   out_users [500000][64]                     (mean over 4 layers, nodes 0..499999)
//   out_items [500000][64]                     (mean over 4 layers, nodes 200000..699999)
//   all_emb   [700000][4][64]                  (x0..x3 per node, layer-interleaved)
//
// Strategy: accumulate each layer directly into the all_emb region of d_out
// ([N][4][64] layout: gather of layer l-1 is a contiguous 256B row slot; the
// scatter-add for layer l lands exactly where the output wants it).

static constexpr int NUSERS = 500000;
static constexpr int NITEMS = 200000;
static constexpr int NNODES = 700000;   // NUSERS + NITEMS
static constexpr int NE     = 5000000;

// --- degree: deg[col[e]] += 1 ------------------------------------------------
__global__ void k_deg(const int* __restrict__ col, float* __restrict__ deg) {
    int e = blockIdx.x * blockDim.x + threadIdx.x;
    if (e < NE) atomicAdd(&deg[col[e]], 1.0f);
}

// --- dinv in place: deg[n] = deg>0 ? rsqrt(deg) : 0 --------------------------
__global__ void k_dinv(float* __restrict__ deg) {
    int n = blockIdx.x * blockDim.x + threadIdx.x;
    if (n < NNODES) {
        float d = deg[n];
        deg[n] = (d > 0.0f) ? rsqrtf(d) : 0.0f;
    }
}

// --- init all_emb: layer0 = concat(user,item); layers 1..3 = 0 ---------------
// One thread per float4 slot. Per node: 64 float4 (4 layers x 16).
__global__ void k_init(const float4* __restrict__ user, const float4* __restrict__ item,
                       float4* __restrict__ all_emb) {
    int i = blockIdx.x * blockDim.x + threadIdx.x;
    if (i >= NNODES * 64) return;            // 44.8M float4 slots
    int node   = i >> 6;
    int within = i & 63;                     // layer*16 + d4
    float4 v;
    if (within < 16) {                       // layer 0: copy source embedding
        v = (node < NUSERS) ? user[node * 16 + within]
                            : item[(node - NUSERS) * 16 + within];
    } else {
        v = make_float4(0.f, 0.f, 0.f, 0.f);
    }
    all_emb[i] = v;
}

// --- propagate layer l: all_emb[c][l][:] += dinv[r]*dinv[c] * all_emb[r][l-1][:]
// 16 threads per edge, each handles one float4 (4 scalar atomics).
__global__ void k_prop(const int* __restrict__ row, const int* __restrict__ col,
                       const float* __restrict__ dinv, float* __restrict__ all_emb,
                       int l) {
    int tid = blockIdx.x * blockDim.x + threadIdx.x;
    if (tid >= NE * 16) return;              // 80M threads
    int e    = tid >> 4;
    int lane = tid & 15;
    int r = row[e];
    int c = col[e];
    float w = dinv[r] * dinv[c];
    float4 v = reinterpret_cast<const float4*>(all_emb)[r * 64 + (l - 1) * 16 + lane];
    float* dst = all_emb + (size_t)c * 256 + l * 64 + lane * 4;
    atomicAdd(dst + 0, w * v.x);
    atomicAdd(dst + 1, w * v.y);
    atomicAdd(dst + 2, w * v.z);
    atomicAdd(dst + 3, w * v.w);
}

// --- outputs: mean over the 4 layer slots ------------------------------------
__global__ void k_out(const float4* __restrict__ all_emb,
                      float4* __restrict__ out_users, float4* __restrict__ out_items) {
    int tid = blockIdx.x * blockDim.x + threadIdx.x;
    if (tid >= NNODES * 16) return;          // 11.2M
    int node = tid >> 4;
    int d4   = tid & 15;
    const float4* p = all_emb + node * 64 + d4;
    float4 a = p[0], b = p[16], c = p[32], d = p[48];
    float4 m;
    m.x = (a.x + b.x + c.x + d.x) * 0.25f;
    m.y = (a.y + b.y + c.y + d.y) * 0.25f;
    m.z = (a.z + b.z + c.z + d.z) * 0.25f;
    m.w = (a.w + b.w + c.w + d.w) * 0.25f;
    if (node < NUSERS)  out_users[node * 16 + d4] = m;
    if (node >= NITEMS) out_items[(node - NITEMS) * 16 + d4] = m;
}

extern "C" void kernel_launch(void* const* d_in, const int* in_sizes, int n_in,
                              void* d_out, int out_size, void* d_ws, size_t ws_size,
                              hipStream_t stream) {
    const float* user  = (const float*)d_in[0];
    const float* item  = (const float*)d_in[1];
    const int*   edges = (const int*)d_in[2];
    const int*   row = edges;            // edge_index[0]
    const int*   col = edges + NE;       // edge_index[1]

    float* out       = (float*)d_out;
    float* out_users = out;                                   // 500000*64
    float* out_items = out + (size_t)NUSERS * 64;             // 500000*64
    float* all_emb   = out + (size_t)NUSERS * 64 * 2;         // 700000*4*64

    float* deg = (float*)d_ws;           // 700000 f32 (zeroed each call)

    const int B = 256;

    hipMemsetAsync(deg, 0, (size_t)NNODES * sizeof(float), stream);
    k_deg <<<(NE + B - 1) / B, B, 0, stream>>>(col, deg);
    k_dinv<<<(NNODES + B - 1) / B, B, 0, stream>>>(deg);
    k_init<<<(NNODES * 64 + B - 1) / B, B, 0, stream>>>(
        (const float4*)user, (const float4*)item, (float4*)all_emb);
    for (int l = 1; l <= 3; ++l) {
        k_prop<<<(NE * 16 + B - 1) / B, B, 0, stream>>>(row, col, deg, all_emb, l);
    }
    k_out<<<(NNODES * 16 + B - 1) / B, B, 0, stream>>>(
        (const float4*)all_emb, (float4*)out_users, (float4*)out_items);
}

// Round 2
// 1586.171 us; speedup vs baseline: 8.3455x; 8.3455x over previous
//
#include <hip/hip_runtime.h>

// LightGCN 3-layer propagation — R2: CSR-gather formulation.
//
// R1 post-mortem: atomic scatter thrashed L2 -> 5.12 GB HBM writes per layer
// (28x the 179 MB destination region). Fix: counting-sort edges by col once
// per call, then per-node register accumulation, one contiguous write per row.
//
// Output (concatenated flat, f32):
//   out_users [500000][64], out_items [500000][64] (nodes 200000..699999),
//   all_emb   [700000][4][64]

static constexpr int NUSERS = 500000;
static constexpr int NITEMS = 200000;
static constexpr int NNODES = 700000;   // NUSERS + NITEMS
static constexpr int NE     = 5000000;
static constexpr int SCAN_B = 1024;
static constexpr int NSB    = (NNODES + SCAN_B - 1) / SCAN_B;   // 684 scan blocks

// --- int degree histogram over col -------------------------------------------
__global__ void k_hist(const int* __restrict__ col, int* __restrict__ deg) {
    int e = blockIdx.x * blockDim.x + threadIdx.x;
    if (e < NE) atomicAdd(&deg[col[e]], 1);
}

// --- per-block exclusive scan (Hillis-Steele in LDS) --------------------------
__global__ void k_scan1(const int* __restrict__ deg, int* __restrict__ offs,
                        int* __restrict__ bsums) {
    __shared__ int s[SCAN_B];
    int t = threadIdx.x;
    int i = blockIdx.x * SCAN_B + t;
    int v = (i < NNODES) ? deg[i] : 0;
    s[t] = v;
    __syncthreads();
    for (int off = 1; off < SCAN_B; off <<= 1) {
        int add = (t >= off) ? s[t - off] : 0;
        __syncthreads();
        s[t] += add;
        __syncthreads();
    }
    if (i < NNODES) offs[i] = s[t] - v;          // exclusive
    if (t == SCAN_B - 1) bsums[blockIdx.x] = s[t];
}

// --- scan the 684 block sums (single block) -----------------------------------
__global__ void k_scan2(int* __restrict__ bsums) {
    __shared__ int s[SCAN_B];
    int t = threadIdx.x;
    int v = (t < NSB) ? bsums[t] : 0;
    s[t] = v;
    __syncthreads();
    for (int off = 1; off < SCAN_B; off <<= 1) {
        int add = (t >= off) ? s[t - off] : 0;
        __syncthreads();
        s[t] += add;
        __syncthreads();
    }
    if (t < NSB) bsums[t] = s[t] - v;            // exclusive block offsets
}

// --- finalize offsets; init cursor copy; dinv ----------------------------------
__global__ void k_scan3(int* __restrict__ offs, const int* __restrict__ bsums,
                        int* __restrict__ cursor, const int* __restrict__ deg,
                        float* __restrict__ dinv) {
    int i = blockIdx.x * blockDim.x + threadIdx.x;
    if (i < NNODES) {
        int o = offs[i] + bsums[i >> 10];
        offs[i]   = o;
        cursor[i] = o;
        int d = deg[i];
        dinv[i] = (d > 0) ? rsqrtf((float)d) : 0.0f;
    }
    if (i == 0) offs[NNODES] = NE;
}

// --- scatter edges into col-sorted order: (row, w) packed 8B ------------------
__global__ void k_scatter(const int* __restrict__ row, const int* __restrict__ col,
                          const float* __restrict__ dinv, int* __restrict__ cursor,
                          int2* __restrict__ srw) {
    int e = blockIdx.x * blockDim.x + threadIdx.x;
    if (e >= NE) return;
    int r = row[e], c = col[e];
    int pos = atomicAdd(&cursor[c], 1);
    float w = dinv[r] * dinv[c];
    srw[pos] = make_int2(r, __float_as_int(w));
}

// --- init all_emb layer 0 only (layers 1..3 fully overwritten by k_prop) -----
__global__ void k_init(const float4* __restrict__ user, const float4* __restrict__ item,
                       float4* __restrict__ all_emb) {
    int tid = blockIdx.x * blockDim.x + threadIdx.x;
    if (tid >= NNODES * 16) return;
    int node = tid >> 4;
    int lane = tid & 15;
    float4 v = (node < NUSERS) ? user[node * 16 + lane]
                               : item[(node - NUSERS) * 16 + lane];
    all_emb[(size_t)node * 64 + lane] = v;
}

// --- propagate layer l: gather + register accumulate, one write per row ------
// 16 threads per node (one float4 of D=64 each).
__global__ void k_prop(const int* __restrict__ offs, const int2* __restrict__ srw,
                       float4* __restrict__ all_emb, int l) {
    int tid = blockIdx.x * blockDim.x + threadIdx.x;
    if (tid >= NNODES * 16) return;
    int n    = tid >> 4;
    int lane = tid & 15;
    int b = offs[n], e = offs[n + 1];
    float4 acc = make_float4(0.f, 0.f, 0.f, 0.f);
    const float4* src = all_emb + (l - 1) * 16 + lane;
    for (int k = b; k < e; ++k) {
        int2 rw = srw[k];
        float w = __int_as_float(rw.y);
        float4 v = src[(size_t)rw.x * 64];
        acc.x += w * v.x; acc.y += w * v.y; acc.z += w * v.z; acc.w += w * v.w;
    }
    all_emb[(size_t)n * 64 + l * 16 + lane] = acc;
}

// --- outputs: mean over the 4 layer slots ------------------------------------
__global__ void k_out(const float4* __restrict__ all_emb,
                      float4* __restrict__ out_users, float4* __restrict__ out_items) {
    int tid = blockIdx.x * blockDim.x + threadIdx.x;
    if (tid >= NNODES * 16) return;
    int node = tid >> 4;
    int d4   = tid & 15;
    const float4* p = all_emb + (size_t)node * 64 + d4;
    float4 a = p[0], b = p[16], c = p[32], d = p[48];
    float4 m;
    m.x = (a.x + b.x + c.x + d.x) * 0.25f;
    m.y = (a.y + b.y + c.y + d.y) * 0.25f;
    m.z = (a.z + b.z + c.z + d.z) * 0.25f;
    m.w = (a.w + b.w + c.w + d.w) * 0.25f;
    if (node < NUSERS)  out_users[node * 16 + d4] = m;
    if (node >= NITEMS) out_items[(node - NITEMS) * 16 + d4] = m;
}

extern "C" void kernel_launch(void* const* d_in, const int* in_sizes, int n_in,
                              void* d_out, int out_size, void* d_ws, size_t ws_size,
                              hipStream_t stream) {
    const float* user  = (const float*)d_in[0];
    const float* item  = (const float*)d_in[1];
    const int*   edges = (const int*)d_in[2];
    const int*   row = edges;            // edge_index[0]
    const int*   col = edges + NE;       // edge_index[1]

    float* out       = (float*)d_out;
    float* out_users = out;
    float* out_items = out + (size_t)NUSERS * 64;
    float* all_emb   = out + (size_t)NUSERS * 64 * 2;   // [700000][4][64]

    // workspace carve (~51 MB)
    char* ws = (char*)d_ws;
    int*   deg    = (int*)ws;                         ws += (size_t)NNODES * 4;
    int*   offs   = (int*)ws;                         ws += (size_t)(NNODES + 1) * 4;
    int*   cursor = (int*)ws;                         ws += (size_t)NNODES * 4;
    int*   bsums  = (int*)ws;                         ws += (size_t)SCAN_B * 4;
    float* dinv   = (float*)ws;                       ws += (size_t)NNODES * 4;
    int2*  srw    = (int2*)ws;                        ws += (size_t)NE * 8;

    const int B = 256;

    hipMemsetAsync(deg, 0, (size_t)NNODES * sizeof(int), stream);
    k_hist <<<(NE + B - 1) / B, B, 0, stream>>>(col, deg);
    k_scan1<<<NSB, SCAN_B, 0, stream>>>(deg, offs, bsums);
    k_scan2<<<1, SCAN_B, 0, stream>>>(bsums);
    k_scan3<<<(NNODES + B - 1) / B, B, 0, stream>>>(offs, bsums, cursor, deg, dinv);
    k_scatter<<<(NE + B - 1) / B, B, 0, stream>>>(row, col, dinv, cursor, srw);
    k_init <<<(NNODES * 16 + B - 1) / B, B, 0, stream>>>(
        (const float4*)user, (const float4*)item, (float4*)all_emb);
    for (int l = 1; l <= 3; ++l) {
        k_prop<<<(NNODES * 16 + B - 1) / B, B, 0, stream>>>(offs, srw, (float4*)all_emb, l);
    }
    k_out<<<(NNODES * 16 + B - 1) / B, B, 0, stream>>>(
        (const float4*)all_emb, (float4*)out_users, (float4*)out_items);
}

// Round 3
// 1301.908 us; speedup vs baseline: 10.1677x; 1.2183x over previous
//
#include <hip/hip_runtime.h>

// LightGCN 3-layer propagation — R3: unrolled CSR gather + fused output mean.
//
// R2 post-mortem: CSR-gather got 13.2ms -> 1.59ms. Remaining est: ~400us/prop,
// which is above the L3-BW floor -> latency-bound inner loop (dependent
// srw -> gather chain, 1 outstanding gather/thread).
// R3: (a) 4x unroll for 4x MLP; (b) fuse mean-output into layer-3 prop
// (saves 716 MB re-read + launch).

static constexpr int NUSERS = 500000;
static constexpr int NITEMS = 200000;
static constexpr int NNODES = 700000;   // NUSERS + NITEMS
static constexpr int NE     = 5000000;
static constexpr int SCAN_B = 1024;
static constexpr int NSB    = (NNODES + SCAN_B - 1) / SCAN_B;   // 684 scan blocks

// --- int degree histogram over col -------------------------------------------
__global__ void k_hist(const int* __restrict__ col, int* __restrict__ deg) {
    int e = blockIdx.x * blockDim.x + threadIdx.x;
    if (e < NE) atomicAdd(&deg[col[e]], 1);
}

// --- per-block exclusive scan (Hillis-Steele in LDS) --------------------------
__global__ void k_scan1(const int* __restrict__ deg, int* __restrict__ offs,
                        int* __restrict__ bsums) {
    __shared__ int s[SCAN_B];
    int t = threadIdx.x;
    int i = blockIdx.x * SCAN_B + t;
    int v = (i < NNODES) ? deg[i] : 0;
    s[t] = v;
    __syncthreads();
    for (int off = 1; off < SCAN_B; off <<= 1) {
        int add = (t >= off) ? s[t - off] : 0;
        __syncthreads();
        s[t] += add;
        __syncthreads();
    }
    if (i < NNODES) offs[i] = s[t] - v;          // exclusive
    if (t == SCAN_B - 1) bsums[blockIdx.x] = s[t];
}

// --- scan the 684 block sums (single block) -----------------------------------
__global__ void k_scan2(int* __restrict__ bsums) {
    __shared__ int s[SCAN_B];
    int t = threadIdx.x;
    int v = (t < NSB) ? bsums[t] : 0;
    s[t] = v;
    __syncthreads();
    for (int off = 1; off < SCAN_B; off <<= 1) {
        int add = (t >= off) ? s[t - off] : 0;
        __syncthreads();
        s[t] += add;
        __syncthreads();
    }
    if (t < NSB) bsums[t] = s[t] - v;            // exclusive block offsets
}

// --- finalize offsets; init cursor copy; dinv ----------------------------------
__global__ void k_scan3(int* __restrict__ offs, const int* __restrict__ bsums,
                        int* __restrict__ cursor, const int* __restrict__ deg,
                        float* __restrict__ dinv) {
    int i = blockIdx.x * blockDim.x + threadIdx.x;
    if (i < NNODES) {
        int o = offs[i] + bsums[i >> 10];
        offs[i]   = o;
        cursor[i] = o;
        int d = deg[i];
        dinv[i] = (d > 0) ? rsqrtf((float)d) : 0.0f;
    }
    if (i == 0) offs[NNODES] = NE;
}

// --- scatter edges into col-sorted order: (row, w) packed 8B ------------------
__global__ void k_scatter(const int* __restrict__ row, const int* __restrict__ col,
                          const float* __restrict__ dinv, int* __restrict__ cursor,
                          int2* __restrict__ srw) {
    int e = blockIdx.x * blockDim.x + threadIdx.x;
    if (e >= NE) return;
    int r = row[e], c = col[e];
    int pos = atomicAdd(&cursor[c], 1);
    float w = dinv[r] * dinv[c];
    srw[pos] = make_int2(r, __float_as_int(w));
}

// --- init all_emb layer 0 (layers 1..3 fully overwritten by k_prop) ----------
__global__ void k_init(const float4* __restrict__ user, const float4* __restrict__ item,
                       float4* __restrict__ all_emb) {
    int tid = blockIdx.x * blockDim.x + threadIdx.x;
    if (tid >= NNODES * 16) return;
    int node = tid >> 4;
    int lane = tid & 15;
    float4 v = (node < NUSERS) ? user[node * 16 + lane]
                               : item[(node - NUSERS) * 16 + lane];
    all_emb[(size_t)node * 64 + lane] = v;
}

// --- propagate layer l: unrolled gather, one write per row -------------------
// 16 threads per node (one float4 of D=64 each). FUSE_OUT: layer 3 epilogue
// also writes the 4-layer mean to out_users/out_items.
template <int L, bool FUSE_OUT>
__global__ void k_prop(const int* __restrict__ offs, const int2* __restrict__ srw,
                       float4* __restrict__ all_emb,
                       float4* __restrict__ out_users, float4* __restrict__ out_items) {
    int tid = blockIdx.x * blockDim.x + threadIdx.x;
    if (tid >= NNODES * 16) return;
    int n    = tid >> 4;
    int lane = tid & 15;
    int b = offs[n], e = offs[n + 1];
    float4 acc = make_float4(0.f, 0.f, 0.f, 0.f);
    const float4* src = all_emb + (L - 1) * 16 + lane;

    int k = b;
    for (; k + 4 <= e; k += 4) {                 // 4x MLP
        int2 rw0 = srw[k + 0];
        int2 rw1 = srw[k + 1];
        int2 rw2 = srw[k + 2];
        int2 rw3 = srw[k + 3];
        float4 v0 = src[(size_t)rw0.x * 64];
        float4 v1 = src[(size_t)rw1.x * 64];
        float4 v2 = src[(size_t)rw2.x * 64];
        float4 v3 = src[(size_t)rw3.x * 64];
        float w0 = __int_as_float(rw0.y), w1 = __int_as_float(rw1.y);
        float w2 = __int_as_float(rw2.y), w3 = __int_as_float(rw3.y);
        acc.x += w0 * v0.x + w1 * v1.x + w2 * v2.x + w3 * v3.x;
        acc.y += w0 * v0.y + w1 * v1.y + w2 * v2.y + w3 * v3.y;
        acc.z += w0 * v0.z + w1 * v1.z + w2 * v2.z + w3 * v3.z;
        acc.w += w0 * v0.w + w1 * v1.w + w2 * v2.w + w3 * v3.w;
    }
    for (; k < e; ++k) {
        int2 rw = srw[k];
        float w = __int_as_float(rw.y);
        float4 v = src[(size_t)rw.x * 64];
        acc.x += w * v.x; acc.y += w * v.y; acc.z += w * v.z; acc.w += w * v.w;
    }

    if (!FUSE_OUT) {
        all_emb[(size_t)n * 64 + L * 16 + lane] = acc;
    } else {
        const float4* p = all_emb + (size_t)n * 64 + lane;
        float4 x0 = p[0], x1 = p[16], x2 = p[32];
        all_emb[(size_t)n * 64 + 48 + lane] = acc;
        float4 m;
        m.x = (x0.x + x1.x + x2.x + acc.x) * 0.25f;
        m.y = (x0.y + x1.y + x2.y + acc.y) * 0.25f;
        m.z = (x0.z + x1.z + x2.z + acc.z) * 0.25f;
        m.w = (x0.w + x1.w + x2.w + acc.w) * 0.25f;
        if (n < NUSERS)  out_users[n * 16 + lane] = m;
        if (n >= NITEMS) out_items[(n - NITEMS) * 16 + lane] = m;
    }
}

extern "C" void kernel_launch(void* const* d_in, const int* in_sizes, int n_in,
                              void* d_out, int out_size, void* d_ws, size_t ws_size,
                              hipStream_t stream) {
    const float* user  = (const float*)d_in[0];
    const float* item  = (const float*)d_in[1];
    const int*   edges = (const int*)d_in[2];
    const int*   row = edges;            // edge_index[0]
    const int*   col = edges + NE;       // edge_index[1]

    float* out       = (float*)d_out;
    float* out_users = out;
    float* out_items = out + (size_t)NUSERS * 64;
    float* all_emb   = out + (size_t)NUSERS * 64 * 2;   // [700000][4][64]

    // workspace carve (~51 MB)
    char* ws = (char*)d_ws;
    int*   deg    = (int*)ws;                         ws += (size_t)NNODES * 4;
    int*   offs   = (int*)ws;                         ws += (size_t)(NNODES + 1) * 4;
    int*   cursor = (int*)ws;                         ws += (size_t)NNODES * 4;
    int*   bsums  = (int*)ws;                         ws += (size_t)SCAN_B * 4;
    float* dinv   = (float*)ws;                       ws += (size_t)NNODES * 4;
    int2*  srw    = (int2*)ws;                        ws += (size_t)NE * 8;

    const int B = 256;
    const int prop_grid = (NNODES * 16 + B - 1) / B;

    hipMemsetAsync(deg, 0, (size_t)NNODES * sizeof(int), stream);
    k_hist <<<(NE + B - 1) / B, B, 0, stream>>>(col, deg);
    k_scan1<<<NSB, SCAN_B, 0, stream>>>(deg, offs, bsums);
    k_scan2<<<1, SCAN_B, 0, stream>>>(bsums);
    k_scan3<<<(NNODES + B - 1) / B, B, 0, stream>>>(offs, bsums, cursor, deg, dinv);
    k_scatter<<<(NE + B - 1) / B, B, 0, stream>>>(row, col, dinv, cursor, srw);
    k_init <<<prop_grid, B, 0, stream>>>(
        (const float4*)user, (const float4*)item, (float4*)all_emb);

    k_prop<1, false><<<prop_grid, B, 0, stream>>>(offs, srw, (float4*)all_emb,
                                                  nullptr, nullptr);
    k_prop<2, false><<<prop_grid, B, 0, stream>>>(offs, srw, (float4*)all_emb,
                                                  nullptr, nullptr);
    k_prop<3, true> <<<prop_grid, B, 0, stream>>>(offs, srw, (float4*)all_emb,
                                                  (float4*)out_users, (float4*)out_items);
}